// Round 13
// baseline (464.115 us; speedup 1.0000x reference)
//
#include <hip/hip_runtime.h>
#include <hip/hip_bf16.h>

// DIAGNOSTIC ROUND: round-11 pipeline bit-for-bit, but gemm1 repeats its full
// work 3x inside one dispatch (idempotent: z1p rewritten with identical values)
// so the dispatch exceeds the harness fillBuffers (~250 us) and surfaces in the
// rocprof top-5 WITH its counters. g = (T_total - 221.5)/2.
//
// B=64, T=2048, D=784, N1=100, N2=10, dt=0.04
// ws: Wg 448000 B | z1p 131072*100 f32 (52.4 MB)

#define FHN_DT 0.04f

typedef _Float16 f16x8 __attribute__((ext_vector_type(8)));
typedef __attribute__((ext_vector_type(4))) float          f32x4;
typedef __attribute__((ext_vector_type(8))) unsigned short ushort8;

__device__ __forceinline__ void sync_lds() {
    asm volatile("s_waitcnt lgkmcnt(0)" ::: "memory");
    __builtin_amdgcn_s_barrier();
    asm volatile("" ::: "memory");
}

// ---------------- prep: W1 (100x784) -> tiled fp16 2-term split image ----------------
// Image: [kt=25][term=2][n=112][40 shorts (32 data + 8 pad)]; term1 = (w-h)*1024
__global__ void prep_w3(const float* __restrict__ W1, unsigned short* __restrict__ Wg) {
    int idx = blockIdx.x * 256 + threadIdx.x;
    if (idx >= 224000) return;
    int sh    = idx % 40;
    int rest  = idx / 40;
    int n     = rest % 112;
    int rest2 = rest / 112;
    int term  = rest2 % 2;
    int kt    = rest2 / 2;
    int k = kt * 32 + sh;
    float v = (n < 100 && sh < 32 && k < 784) ? W1[n * 784 + k] : 0.0f;
    _Float16 h = (_Float16)v;
    _Float16 l = (_Float16)((v - (float)h) * 1024.0f);
    Wg[idx] = (term == 0) ? __builtin_bit_cast(unsigned short, h)
                          : __builtin_bit_cast(unsigned short, l);
}

// ---------------- GEMM1 (x3 reps): 3-term fp16 split, BM=128 (rt=2), BK=32 ----------------
#define GW_TILE 8960     // shorts per K-tile (2 terms x 112 x 40)

__global__ __launch_bounds__(256, 2) void gemm1_n3(const float* __restrict__ A,
                                                   const unsigned short* __restrict__ Wg,
                                                   float* __restrict__ z1p) {
    __shared__ __align__(16) unsigned short Wl[2][GW_TILE];   // 35840 B
    const int tid  = threadIdx.x;
    const int w    = tid >> 6;
    const int lane = tid & 63;
    const int ln   = lane & 15;
    const int kg   = lane >> 4;                  // k-slice = kg*8
    const long row0 = (long)blockIdx.x * 128;

    const float* arow0 = A + (row0 + w * 32 + ln) * 784 + kg * 8;
    const float* arow1 = arow0 + (size_t)16 * 784;

#define ISSUE_A(T, AF) {                                                        \
        if ((T) == 24 && kg >= 2) {                                             \
            *(float4*)&AF[0]  = make_float4(0.f, 0.f, 0.f, 0.f);                \
            *(float4*)&AF[4]  = make_float4(0.f, 0.f, 0.f, 0.f);                \
            *(float4*)&AF[8]  = make_float4(0.f, 0.f, 0.f, 0.f);                \
            *(float4*)&AF[12] = make_float4(0.f, 0.f, 0.f, 0.f);                \
        } else {                                                                \
            *(float4*)&AF[0]  = *(const float4*)(arow0 + (T) * 32);             \
            *(float4*)&AF[4]  = *(const float4*)(arow0 + (T) * 32 + 4);         \
            *(float4*)&AF[8]  = *(const float4*)(arow1 + (T) * 32);             \
            *(float4*)&AF[12] = *(const float4*)(arow1 + (T) * 32 + 4);         \
        } }

#define LOADW(T) {                                                              \
        _Pragma("unroll")                                                       \
        for (int j_ = 0; j_ < 5; ++j_) {                                        \
            int off_ = j_ * 4096 + tid * 16;                                    \
            if (off_ < 17920)                                                   \
                wreg[j_] = *(const ushort8*)((const char*)Wg                    \
                            + (size_t)(T) * 17920 + off_);                      \
        } }

#define BODY(KT, AF) {                                                          \
        f16x8 ah0, al0, ah1, al1;                                               \
        _Pragma("unroll")                                                       \
        for (int e_ = 0; e_ < 8; ++e_) {                                        \
            float a0_ = AF[e_], a1_ = AF[8 + e_];                               \
            _Float16 h0_ = (_Float16)a0_, h1_ = (_Float16)a1_;                  \
            ah0[e_] = h0_; ah1[e_] = h1_;                                       \
            al0[e_] = (_Float16)((a0_ - (float)h0_) * 1024.0f);                 \
            al1[e_] = (_Float16)((a1_ - (float)h1_) * 1024.0f);                 \
        }                                                                       \
        {                                                                       \
            unsigned short* buf_ = &Wl[(KT) & 1][0];                            \
            _Pragma("unroll")                                                   \
            for (int j_ = 0; j_ < 5; ++j_) {                                    \
                int off_ = j_ * 4096 + tid * 16;                                \
                if (off_ < 17920) *(ushort8*)((char*)buf_ + off_) = wreg[j_];   \
            }                                                                   \
        }                                                                       \
        if ((KT) < 24) LOADW((KT) + 1);                                         \
        if ((KT) < 23) ISSUE_A((KT) + 2, AF);                                   \
        sync_lds();                                                             \
        const unsigned short* cb_ = &Wl[(KT) & 1][0];                           \
        _Pragma("unroll")                                                       \
        for (int ct_ = 0; ct_ < 7; ++ct_) {                                     \
            const unsigned short* pw_ = cb_ + (ct_ * 16 + ln) * 40 + kg * 8;    \
            f16x8 bh = *(const f16x8*)(pw_);                                    \
            f16x8 bl = *(const f16x8*)(pw_ + 4480);                             \
            acc1[0][ct_] = __builtin_amdgcn_mfma_f32_16x16x32_f16(ah0, bh, acc1[0][ct_], 0, 0, 0); \
            acc2[0][ct_] = __builtin_amdgcn_mfma_f32_16x16x32_f16(ah0, bl, acc2[0][ct_], 0, 0, 0); \
            acc2[0][ct_] = __builtin_amdgcn_mfma_f32_16x16x32_f16(al0, bh, acc2[0][ct_], 0, 0, 0); \
            acc1[1][ct_] = __builtin_amdgcn_mfma_f32_16x16x32_f16(ah1, bh, acc1[1][ct_], 0, 0, 0); \
            acc2[1][ct_] = __builtin_amdgcn_mfma_f32_16x16x32_f16(ah1, bl, acc2[1][ct_], 0, 0, 0); \
            acc2[1][ct_] = __builtin_amdgcn_mfma_f32_16x16x32_f16(al1, bh, acc2[1][ct_], 0, 0, 0); \
        } }

#pragma unroll 1
    for (int rep = 0; rep < 3; ++rep) {
        f32x4 acc1[2][7] = {};
        f32x4 acc2[2][7] = {};
        float afpA[16], afpB[16];
        ushort8 wreg[5];

        LOADW(0);
        ISSUE_A(0, afpA);
        ISSUE_A(1, afpB);

#pragma unroll 1
        for (int kt2 = 0; kt2 < 12; ++kt2) {
            BODY(kt2 * 2,     afpA);
            BODY(kt2 * 2 + 1, afpB);
        }
        BODY(24, afpA);

        // epilogue: C/D map col = lane&15, row = kg*4 + r ; z = acc1 + acc2/1024
#pragma unroll
        for (int ct = 0; ct < 7; ++ct) {
            int n = ct * 16 + ln;
            if (n < 100) {
#pragma unroll
                for (int rt = 0; rt < 2; ++rt) {
                    long rg = row0 + w * 32 + rt * 16 + kg * 4;
                    float* p = z1p + rg * 100 + n;
#pragma unroll
                    for (int r = 0; r < 4; ++r)
                        p[r * 100] = fmaf(acc2[rt][ct][r], 0.0009765625f, acc1[rt][ct][r]);
                }
            }
        }
        // protect Wl[0] (read by BODY(24)) from next rep's STOREW(0)
        sync_lds();
    }
#undef ISSUE_A
#undef LOADW
#undef BODY
}

// ---------------- fused scan1 + gemm2 + scan2 (round-11 version, unchanged) ----------------
__global__ __launch_bounds__(512) void fused_scan(const float* __restrict__ z1p,
                                                  const float* __restrict__ W2,
                                                  float* __restrict__ out) {
    __shared__ float fsm[32768];
    const int tid = threadIdx.x;
    const int b   = blockIdx.x;
    const float dt = FHN_DT;

    float V = 0.f, S = 0.f;
    const float* zb = z1p + (long)b * 2048 * 100 + tid;   // scan1 lanes only
    float z0[16], z1r[16], z2r[16], z3r[16];
    if (tid < 100) {
#pragma unroll
        for (int u = 0; u < 16; ++u) {
            z0[u]  = zb[u * 100];
            z1r[u] = zb[(16 + u) * 100];
            z2r[u] = zb[(32 + u) * 100];
            z3r[u] = zb[(48 + u) * 100];
        }
    }

    const int tg = tid - 128;
    int pp = tg >> 7;                                     // wave-uniform for tid>=128
    pp = __builtin_amdgcn_readfirstlane(pp);
    const int r  = tg & 127;
    const int mb = (pp == 0) ? 0 : (pp == 1 ? 4 : 7);
    const int mc = (pp == 0) ? 4 : 3;

    for (int i = 0; i <= 18; ++i) {
        if (tid < 128) {
            bool a1 = (tid < 100) && (i < 16);
            bool a2 = (tid >= 100) && (tid < 110) && (i >= 2) && (i < 18);
            if (a1 || a2) {
                const int cw = i & 1;
#pragma unroll
                for (int sub = 0; sub < 8; ++sub) {
                    float zt[16];
                    if (a1) {
                        int tn = (i * 8 + sub + 4) * 16;
                        if (tn < 2048) {
#pragma unroll
                            for (int u = 0; u < 16; ++u) zt[u] = zb[(tn + u) * 100];
                        }
                    }
                    if (a2) {
#pragma unroll
                        for (int u = 0; u < 16; ++u)
                            z0[u] = fsm[29696 + cw * 1536 + (sub * 16 + u) * 12 + (tid - 100)];
                    }
#pragma unroll
                    for (int u = 0; u < 16; ++u) {
                        int tl = sub * 16 + u;
                        fsm[cw * 14848 + tl * 116 + tid] = V;
                        float z  = z0[u];
                        float V3 = V * V * V;
                        float Vn = fmaf(1.f + dt, V,
                                    fmaf(-dt / 3.f, V3, fmaf(-dt, S, dt * z)));
                        float Sn = fmaf(dt * 0.08f, V + 0.7f - 0.8f * S, S);
                        V = Vn; S = Sn;
                    }
                    if (a1) {
#pragma unroll
                        for (int u = 0; u < 16; ++u) {
                            z0[u] = z1r[u]; z1r[u] = z2r[u]; z2r[u] = z3r[u]; z3r[u] = zt[u];
                        }
                    }
                }
            }
        } else {
            if (i >= 1 && i <= 16) {
                const int pb = (i - 1) & 1;
                float acc[4] = {0.f, 0.f, 0.f, 0.f};
                for (int kq = 0; kq < 25; ++kq) {
                    float4 v = *(const float4*)&fsm[pb * 14848 + r * 116 + kq * 4];
#pragma unroll
                    for (int j = 0; j < 4; ++j) {
                        if (j < mc) {
                            const float* wp = W2 + (mb + j) * 100 + kq * 4;  // uniform -> s_load
                            acc[j] = fmaf(v.x, wp[0], acc[j]);
                            acc[j] = fmaf(v.y, wp[1], acc[j]);
                            acc[j] = fmaf(v.z, wp[2], acc[j]);
                            acc[j] = fmaf(v.w, wp[3], acc[j]);
                        }
                    }
                }
#pragma unroll
                for (int j = 0; j < 4; ++j)
                    if (j < mc) fsm[29696 + pb * 1536 + r * 12 + mb + j] = 0.5f * acc[j];
            }
            if (i >= 3) {
                const int pb = (i - 1) & 1;
                float* dst = out + ((long)b * 2048 + (long)(i - 3) * 128 + r) * 10;
#pragma unroll
                for (int j = 0; j < 4; ++j)
                    if (j < mc) dst[mb + j] = fsm[pb * 14848 + r * 116 + 100 + mb + j];
            }
        }
        sync_lds();
    }
}

extern "C" void kernel_launch(void* const* d_in, const int* in_sizes, int n_in,
                              void* d_out, int out_size, void* d_ws, size_t ws_size,
                              hipStream_t stream) {
    const float* batch = (const float*)d_in[0];   // 64*2048*784
    const float* W1    = (const float*)d_in[1];   // 100*784
    const float* W2    = (const float*)d_in[2];   // 10*100
    float* out = (float*)d_out;                   // 64*2048*10

    char* base = (char*)d_ws;
    unsigned short* Wg = (unsigned short*)base;   // 448000 B
    float* z1p = (float*)(base + 448000);         // 131072*100 f32

    prep_w3<<<875, 256, 0, stream>>>(W1, Wg);
    gemm1_n3<<<1024, 256, 0, stream>>>(batch, Wg, z1p);
    fused_scan<<<64, 512, 0, stream>>>(z1p, W2, out);
}

// Round 14
// 319.944 us; speedup vs baseline: 1.4506x; 1.4506x over previous
//
#include <hip/hip_runtime.h>
#include <hip/hip_bf16.h>

// B=64, T=2048, D=784, N1=100, N2=10, dt=0.04
// Pipeline:
//   prep_w3  : W1 -> fp16 2-way split (h, r*1024), per-K-tile image [25][2][112][40]
//   gemm1_n  : z1 = batch @ W1^T, 3-term fp16 split MFMA 16x16x32 (round-11 verbatim)
//   scan1_k  : standalone FHN scan1 — 6400 independent chains on 50 blocks
//              (was fused; unfusing gives 6x CU coverage for the serial chains)
//   fused2   : V1-staging + gemm2 + scan2 + copy-out (fused_scan minus scan1;
//              staging reg-buffered: load -> gemm2 -> LDS-write -> barrier)
//
// ws: Wg 448000 B | z1p 52428800 B | V1 52428800 B  (~105 MB)

#define FHN_DT 0.04f

typedef _Float16 f16x8 __attribute__((ext_vector_type(8)));
typedef __attribute__((ext_vector_type(4))) float          f32x4;
typedef __attribute__((ext_vector_type(8))) unsigned short ushort8;

__device__ __forceinline__ void sync_lds() {
    asm volatile("s_waitcnt lgkmcnt(0)" ::: "memory");
    __builtin_amdgcn_s_barrier();
    asm volatile("" ::: "memory");
}

// ---------------- prep: W1 (100x784) -> tiled fp16 2-term split image ----------------
__global__ void prep_w3(const float* __restrict__ W1, unsigned short* __restrict__ Wg) {
    int idx = blockIdx.x * 256 + threadIdx.x;
    if (idx >= 224000) return;
    int sh    = idx % 40;
    int rest  = idx / 40;
    int n     = rest % 112;
    int rest2 = rest / 112;
    int term  = rest2 % 2;
    int kt    = rest2 / 2;
    int k = kt * 32 + sh;
    float v = (n < 100 && sh < 32 && k < 784) ? W1[n * 784 + k] : 0.0f;
    _Float16 h = (_Float16)v;
    _Float16 l = (_Float16)((v - (float)h) * 1024.0f);
    Wg[idx] = (term == 0) ? __builtin_bit_cast(unsigned short, h)
                          : __builtin_bit_cast(unsigned short, l);
}

// ---------------- GEMM1: 3-term fp16 split, BM=128 (rt=2), BK=32 (round-11 verbatim) ----------------
#define GW_TILE 8960

__global__ __launch_bounds__(256, 2) void gemm1_n(const float* __restrict__ A,
                                                  const unsigned short* __restrict__ Wg,
                                                  float* __restrict__ z1p) {
    __shared__ __align__(16) unsigned short Wl[2][GW_TILE];
    const int tid  = threadIdx.x;
    const int w    = tid >> 6;
    const int lane = tid & 63;
    const int ln   = lane & 15;
    const int kg   = lane >> 4;
    const long row0 = (long)blockIdx.x * 128;

    const float* arow0 = A + (row0 + w * 32 + ln) * 784 + kg * 8;
    const float* arow1 = arow0 + (size_t)16 * 784;

    f32x4 acc1[2][7] = {};
    f32x4 acc2[2][7] = {};
    float afpA[16], afpB[16];
    ushort8 wreg[5];

#define ISSUE_A(T, AF) {                                                        \
        if ((T) == 24 && kg >= 2) {                                             \
            *(float4*)&AF[0]  = make_float4(0.f, 0.f, 0.f, 0.f);                \
            *(float4*)&AF[4]  = make_float4(0.f, 0.f, 0.f, 0.f);                \
            *(float4*)&AF[8]  = make_float4(0.f, 0.f, 0.f, 0.f);                \
            *(float4*)&AF[12] = make_float4(0.f, 0.f, 0.f, 0.f);                \
        } else {                                                                \
            *(float4*)&AF[0]  = *(const float4*)(arow0 + (T) * 32);             \
            *(float4*)&AF[4]  = *(const float4*)(arow0 + (T) * 32 + 4);         \
            *(float4*)&AF[8]  = *(const float4*)(arow1 + (T) * 32);             \
            *(float4*)&AF[12] = *(const float4*)(arow1 + (T) * 32 + 4);         \
        } }

#define LOADW(T) {                                                              \
        _Pragma("unroll")                                                       \
        for (int j_ = 0; j_ < 5; ++j_) {                                        \
            int off_ = j_ * 4096 + tid * 16;                                    \
            if (off_ < 17920)                                                   \
                wreg[j_] = *(const ushort8*)((const char*)Wg                    \
                            + (size_t)(T) * 17920 + off_);                      \
        } }

#define BODY(KT, AF) {                                                          \
        f16x8 ah0, al0, ah1, al1;                                               \
        _Pragma("unroll")                                                       \
        for (int e_ = 0; e_ < 8; ++e_) {                                        \
            float a0_ = AF[e_], a1_ = AF[8 + e_];                               \
            _Float16 h0_ = (_Float16)a0_, h1_ = (_Float16)a1_;                  \
            ah0[e_] = h0_; ah1[e_] = h1_;                                       \
            al0[e_] = (_Float16)((a0_ - (float)h0_) * 1024.0f);                 \
            al1[e_] = (_Float16)((a1_ - (float)h1_) * 1024.0f);                 \
        }                                                                       \
        {                                                                       \
            unsigned short* buf_ = &Wl[(KT) & 1][0];                            \
            _Pragma("unroll")                                                   \
            for (int j_ = 0; j_ < 5; ++j_) {                                    \
                int off_ = j_ * 4096 + tid * 16;                                \
                if (off_ < 17920) *(ushort8*)((char*)buf_ + off_) = wreg[j_];   \
            }                                                                   \
        }                                                                       \
        if ((KT) < 24) LOADW((KT) + 1);                                         \
        if ((KT) < 23) ISSUE_A((KT) + 2, AF);                                   \
        sync_lds();                                                             \
        const unsigned short* cb_ = &Wl[(KT) & 1][0];                           \
        _Pragma("unroll")                                                       \
        for (int ct_ = 0; ct_ < 7; ++ct_) {                                     \
            const unsigned short* pw_ = cb_ + (ct_ * 16 + ln) * 40 + kg * 8;    \
            f16x8 bh = *(const f16x8*)(pw_);                                    \
            f16x8 bl = *(const f16x8*)(pw_ + 4480);                             \
            acc1[0][ct_] = __builtin_amdgcn_mfma_f32_16x16x32_f16(ah0, bh, acc1[0][ct_], 0, 0, 0); \
            acc2[0][ct_] = __builtin_amdgcn_mfma_f32_16x16x32_f16(ah0, bl, acc2[0][ct_], 0, 0, 0); \
            acc2[0][ct_] = __builtin_amdgcn_mfma_f32_16x16x32_f16(al0, bh, acc2[0][ct_], 0, 0, 0); \
            acc1[1][ct_] = __builtin_amdgcn_mfma_f32_16x16x32_f16(ah1, bh, acc1[1][ct_], 0, 0, 0); \
            acc2[1][ct_] = __builtin_amdgcn_mfma_f32_16x16x32_f16(ah1, bl, acc2[1][ct_], 0, 0, 0); \
            acc2[1][ct_] = __builtin_amdgcn_mfma_f32_16x16x32_f16(al1, bh, acc2[1][ct_], 0, 0, 0); \
        } }

    LOADW(0);
    ISSUE_A(0, afpA);
    ISSUE_A(1, afpB);

    for (int kt2 = 0; kt2 < 12; ++kt2) {
        BODY(kt2 * 2,     afpA);
        BODY(kt2 * 2 + 1, afpB);
    }
    BODY(24, afpA);

#pragma unroll
    for (int ct = 0; ct < 7; ++ct) {
        int n = ct * 16 + ln;
        if (n < 100) {
#pragma unroll
            for (int rt = 0; rt < 2; ++rt) {
                long rg = row0 + w * 32 + rt * 16 + kg * 4;
                float* p = z1p + rg * 100 + n;
#pragma unroll
                for (int r = 0; r < 4; ++r)
                    p[r * 100] = fmaf(acc2[rt][ct][r], 0.0009765625f, acc1[rt][ct][r]);
            }
        }
    }
#undef ISSUE_A
#undef LOADW
#undef BODY
}

// ---------------- scan1: standalone, 6400 chains, 50 blocks x 128 ----------------
// FHN arithmetic + 4-deep/16-group prefetch copied verbatim from fused_scan's a1 path.
__global__ __launch_bounds__(128) void scan1_k(const float* __restrict__ z1p,
                                               float* __restrict__ V1) {
    int c = blockIdx.x * 128 + threadIdx.x;
    if (c >= 6400) return;
    int b = c / 100, n = c % 100;
    const float dt = FHN_DT;
    const float* zb = z1p + (long)b * 204800 + n;
    float* vb = V1 + (long)b * 204800 + n;
    float V = 0.f, S = 0.f;
    float z0[16], z1r[16], z2r[16], z3r[16];
#pragma unroll
    for (int u = 0; u < 16; ++u) {
        z0[u]  = zb[u * 100];
        z1r[u] = zb[(16 + u) * 100];
        z2r[u] = zb[(32 + u) * 100];
        z3r[u] = zb[(48 + u) * 100];
    }
    for (int g = 0; g < 128; ++g) {
        float zt[16];
        int tn = (g + 4) * 16;
        if (tn < 2048) {
#pragma unroll
            for (int u = 0; u < 16; ++u) zt[u] = zb[(tn + u) * 100];
        }
#pragma unroll
        for (int u = 0; u < 16; ++u) {
            vb[(g * 16 + u) * 100] = V;
            float z  = z0[u];
            float V3 = V * V * V;
            float Vn = fmaf(1.f + dt, V,
                        fmaf(-dt / 3.f, V3, fmaf(-dt, S, dt * z)));
            float Sn = fmaf(dt * 0.08f, V + 0.7f - 0.8f * S, S);
            V = Vn; S = Sn;
        }
#pragma unroll
        for (int u = 0; u < 16; ++u) {
            z0[u] = z1r[u]; z1r[u] = z2r[u]; z2r[u] = z3r[u]; z3r[u] = zt[u];
        }
    }
}

// ---------------- fused2: V1 staging + gemm2 + scan2 + copy-out ----------------
// 64 blocks x 512. Same LDS map / skew / indexing as fused_scan; scan1 lanes
// replaced by reg-buffered staging on tid>=128 (load -> gemm2 -> LDS write).
__global__ __launch_bounds__(512) void fused2(const float* __restrict__ V1,
                                              const float* __restrict__ W2,
                                              float* __restrict__ out) {
    __shared__ float fsm[32768];
    const int tid = threadIdx.x;
    const int b   = blockIdx.x;
    const float dt = FHN_DT;
    float V = 0.f, S = 0.f;

    const int tg = tid - 128;
    int pp = tg >> 7;
    pp = __builtin_amdgcn_readfirstlane(pp);
    const int r  = tg & 127;
    const int mb = (pp == 0) ? 0 : (pp == 1 ? 4 : 7);
    const int mc = (pp == 0) ? 4 : 3;

    for (int i = 0; i <= 18; ++i) {
        if (tid < 128) {
            // scan2 lanes: tid 100..109, chunk i-2
            bool a2 = (tid >= 100) && (tid < 110) && (i >= 2) && (i < 18);
            if (a2) {
                const int cw = i & 1;
#pragma unroll
                for (int sub = 0; sub < 8; ++sub) {
                    float z0s[16];
#pragma unroll
                    for (int u = 0; u < 16; ++u)
                        z0s[u] = fsm[29696 + cw * 1536 + (sub * 16 + u) * 12 + (tid - 100)];
#pragma unroll
                    for (int u = 0; u < 16; ++u) {
                        int tl = sub * 16 + u;
                        fsm[cw * 14848 + tl * 116 + tid] = V;
                        float z  = z0s[u];
                        float V3 = V * V * V;
                        float Vn = fmaf(1.f + dt, V,
                                    fmaf(-dt / 3.f, V3, fmaf(-dt, S, dt * z)));
                        float Sn = fmaf(dt * 0.08f, V + 0.7f - 0.8f * S, S);
                        V = Vn; S = Sn;
                    }
                }
            }
        } else {
            float4 sreg[9];
            const bool st = (i < 16);
            // (a) issue stage loads for chunk i (linear, coalesced)
            if (st) {
                const float* src = V1 + (long)b * 204800 + (long)i * 12800;
#pragma unroll
                for (int j = 0; j < 9; ++j) {
                    int f = j * 384 + tg;
                    if (f < 3200) sreg[j] = *(const float4*)(src + f * 4);
                }
            }
            // (b) gemm2 chunk i-1 (verbatim)
            if (i >= 1 && i <= 16) {
                const int pb = (i - 1) & 1;
                float acc[4] = {0.f, 0.f, 0.f, 0.f};
                for (int kq = 0; kq < 25; ++kq) {
                    float4 v = *(const float4*)&fsm[pb * 14848 + r * 116 + kq * 4];
#pragma unroll
                    for (int j = 0; j < 4; ++j) {
                        if (j < mc) {
                            const float* wp = W2 + (mb + j) * 100 + kq * 4;
                            acc[j] = fmaf(v.x, wp[0], acc[j]);
                            acc[j] = fmaf(v.y, wp[1], acc[j]);
                            acc[j] = fmaf(v.z, wp[2], acc[j]);
                            acc[j] = fmaf(v.w, wp[3], acc[j]);
                        }
                    }
                }
#pragma unroll
                for (int j = 0; j < 4; ++j)
                    if (j < mc) fsm[29696 + pb * 1536 + r * 12 + mb + j] = 0.5f * acc[j];
            }
            // (c) stage write chunk i into fsm[i&1] cols 0..99 (rows of 25 float4)
            if (st) {
                const int cw = i & 1;
#pragma unroll
                for (int j = 0; j < 9; ++j) {
                    int f = j * 384 + tg;
                    if (f < 3200) {
                        int rr = f / 25, c4 = f % 25;
                        *(float4*)&fsm[cw * 14848 + rr * 116 + c4 * 4] = sreg[j];
                    }
                }
            }
            // (d) copy-out chunk i-3 (verbatim)
            if (i >= 3) {
                const int pb = (i - 1) & 1;
                float* dst = out + ((long)b * 2048 + (long)(i - 3) * 128 + r) * 10;
#pragma unroll
                for (int j = 0; j < 4; ++j)
                    if (j < mc) dst[mb + j] = fsm[pb * 14848 + r * 116 + 100 + mb + j];
            }
        }
        sync_lds();
    }
}

extern "C" void kernel_launch(void* const* d_in, const int* in_sizes, int n_in,
                              void* d_out, int out_size, void* d_ws, size_t ws_size,
                              hipStream_t stream) {
    const float* batch = (const float*)d_in[0];   // 64*2048*784
    const float* W1    = (const float*)d_in[1];   // 100*784
    const float* W2    = (const float*)d_in[2];   // 10*100
    float* out = (float*)d_out;                   // 64*2048*10

    char* base = (char*)d_ws;
    unsigned short* Wg = (unsigned short*)base;            // 448000 B
    float* z1p = (float*)(base + 448000);                  // 131072*100 f32
    float* V1  = z1p + (size_t)131072 * 100;               // 131072*100 f32

    prep_w3<<<875, 256, 0, stream>>>(W1, Wg);
    gemm1_n<<<1024, 256, 0, stream>>>(batch, Wg, z1p);
    scan1_k<<<50, 128, 0, stream>>>(z1p, V1);
    fused2<<<64, 512, 0, stream>>>(V1, W2, out);
}

// Round 15
// 204.299 us; speedup vs baseline: 2.2717x; 1.5661x over previous
//
#include <hip/hip_runtime.h>
#include <hip/hip_bf16.h>

// B=64, T=2048, D=784, N1=100, N2=10, dt=0.04
// Pipeline (round-11 revert + one fix):
//   prep_w3  : W1 -> fp16 2-way split (h, r*1024), per-K-tile image [25][2][112][40]
//   gemm1_n  : z1 = batch @ W1^T, 3-term fp16 split MFMA 16x16x32 (round-11 verbatim)
//   fused_scan3: scan1 + gemm2 + scan2, 576 threads. FIX vs r11: scan2 moved from
//              tid 100-109 (same wave as scan1's upper lanes -> the wave ran BOTH
//              128-step FHN chains serially each iteration) to its own wave
//              (tid 512-521). Waves: 0-1 scan1, 2-7 gemm2+copyout, 8 scan2.
//
// ws: Wg 448000 B | z1p 131072*100 f32 (52.4 MB)

#define FHN_DT 0.04f

typedef _Float16 f16x8 __attribute__((ext_vector_type(8)));
typedef __attribute__((ext_vector_type(4))) float          f32x4;
typedef __attribute__((ext_vector_type(8))) unsigned short ushort8;

__device__ __forceinline__ void sync_lds() {
    asm volatile("s_waitcnt lgkmcnt(0)" ::: "memory");
    __builtin_amdgcn_s_barrier();
    asm volatile("" ::: "memory");
}

// ---------------- prep: W1 (100x784) -> tiled fp16 2-term split image ----------------
__global__ void prep_w3(const float* __restrict__ W1, unsigned short* __restrict__ Wg) {
    int idx = blockIdx.x * 256 + threadIdx.x;
    if (idx >= 224000) return;
    int sh    = idx % 40;
    int rest  = idx / 40;
    int n     = rest % 112;
    int rest2 = rest / 112;
    int term  = rest2 % 2;
    int kt    = rest2 / 2;
    int k = kt * 32 + sh;
    float v = (n < 100 && sh < 32 && k < 784) ? W1[n * 784 + k] : 0.0f;
    _Float16 h = (_Float16)v;
    _Float16 l = (_Float16)((v - (float)h) * 1024.0f);
    Wg[idx] = (term == 0) ? __builtin_bit_cast(unsigned short, h)
                          : __builtin_bit_cast(unsigned short, l);
}

// ---------------- GEMM1: 3-term fp16 split, BM=128 (rt=2), BK=32 (round-11 verbatim) ----------------
#define GW_TILE 8960

__global__ __launch_bounds__(256, 2) void gemm1_n(const float* __restrict__ A,
                                                  const unsigned short* __restrict__ Wg,
                                                  float* __restrict__ z1p) {
    __shared__ __align__(16) unsigned short Wl[2][GW_TILE];
    const int tid  = threadIdx.x;
    const int w    = tid >> 6;
    const int lane = tid & 63;
    const int ln   = lane & 15;
    const int kg   = lane >> 4;
    const long row0 = (long)blockIdx.x * 128;

    const float* arow0 = A + (row0 + w * 32 + ln) * 784 + kg * 8;
    const float* arow1 = arow0 + (size_t)16 * 784;

    f32x4 acc1[2][7] = {};
    f32x4 acc2[2][7] = {};
    float afpA[16], afpB[16];
    ushort8 wreg[5];

#define ISSUE_A(T, AF) {                                                        \
        if ((T) == 24 && kg >= 2) {                                             \
            *(float4*)&AF[0]  = make_float4(0.f, 0.f, 0.f, 0.f);                \
            *(float4*)&AF[4]  = make_float4(0.f, 0.f, 0.f, 0.f);                \
            *(float4*)&AF[8]  = make_float4(0.f, 0.f, 0.f, 0.f);                \
            *(float4*)&AF[12] = make_float4(0.f, 0.f, 0.f, 0.f);                \
        } else {                                                                \
            *(float4*)&AF[0]  = *(const float4*)(arow0 + (T) * 32);             \
            *(float4*)&AF[4]  = *(const float4*)(arow0 + (T) * 32 + 4);         \
            *(float4*)&AF[8]  = *(const float4*)(arow1 + (T) * 32);             \
            *(float4*)&AF[12] = *(const float4*)(arow1 + (T) * 32 + 4);         \
        } }

#define LOADW(T) {                                                              \
        _Pragma("unroll")                                                       \
        for (int j_ = 0; j_ < 5; ++j_) {                                        \
            int off_ = j_ * 4096 + tid * 16;                                    \
            if (off_ < 17920)                                                   \
                wreg[j_] = *(const ushort8*)((const char*)Wg                    \
                            + (size_t)(T) * 17920 + off_);                      \
        } }

#define BODY(KT, AF) {                                                          \
        f16x8 ah0, al0, ah1, al1;                                               \
        _Pragma("unroll")                                                       \
        for (int e_ = 0; e_ < 8; ++e_) {                                        \
            float a0_ = AF[e_], a1_ = AF[8 + e_];                               \
            _Float16 h0_ = (_Float16)a0_, h1_ = (_Float16)a1_;                  \
            ah0[e_] = h0_; ah1[e_] = h1_;                                       \
            al0[e_] = (_Float16)((a0_ - (float)h0_) * 1024.0f);                 \
            al1[e_] = (_Float16)((a1_ - (float)h1_) * 1024.0f);                 \
        }                                                                       \
        {                                                                       \
            unsigned short* buf_ = &Wl[(KT) & 1][0];                            \
            _Pragma("unroll")                                                   \
            for (int j_ = 0; j_ < 5; ++j_) {                                    \
                int off_ = j_ * 4096 + tid * 16;                                \
                if (off_ < 17920) *(ushort8*)((char*)buf_ + off_) = wreg[j_];   \
            }                                                                   \
        }                                                                       \
        if ((KT) < 24) LOADW((KT) + 1);                                         \
        if ((KT) < 23) ISSUE_A((KT) + 2, AF);                                   \
        sync_lds();                                                             \
        const unsigned short* cb_ = &Wl[(KT) & 1][0];                           \
        _Pragma("unroll")                                                       \
        for (int ct_ = 0; ct_ < 7; ++ct_) {                                     \
            const unsigned short* pw_ = cb_ + (ct_ * 16 + ln) * 40 + kg * 8;    \
            f16x8 bh = *(const f16x8*)(pw_);                                    \
            f16x8 bl = *(const f16x8*)(pw_ + 4480);                             \
            acc1[0][ct_] = __builtin_amdgcn_mfma_f32_16x16x32_f16(ah0, bh, acc1[0][ct_], 0, 0, 0); \
            acc2[0][ct_] = __builtin_amdgcn_mfma_f32_16x16x32_f16(ah0, bl, acc2[0][ct_], 0, 0, 0); \
            acc2[0][ct_] = __builtin_amdgcn_mfma_f32_16x16x32_f16(al0, bh, acc2[0][ct_], 0, 0, 0); \
            acc1[1][ct_] = __builtin_amdgcn_mfma_f32_16x16x32_f16(ah1, bh, acc1[1][ct_], 0, 0, 0); \
            acc2[1][ct_] = __builtin_amdgcn_mfma_f32_16x16x32_f16(ah1, bl, acc2[1][ct_], 0, 0, 0); \
            acc2[1][ct_] = __builtin_amdgcn_mfma_f32_16x16x32_f16(al1, bh, acc2[1][ct_], 0, 0, 0); \
        } }

    LOADW(0);
    ISSUE_A(0, afpA);
    ISSUE_A(1, afpB);

    for (int kt2 = 0; kt2 < 12; ++kt2) {
        BODY(kt2 * 2,     afpA);
        BODY(kt2 * 2 + 1, afpB);
    }
    BODY(24, afpA);

#pragma unroll
    for (int ct = 0; ct < 7; ++ct) {
        int n = ct * 16 + ln;
        if (n < 100) {
#pragma unroll
            for (int rt = 0; rt < 2; ++rt) {
                long rg = row0 + w * 32 + rt * 16 + kg * 4;
                float* p = z1p + rg * 100 + n;
#pragma unroll
                for (int r = 0; r < 4; ++r)
                    p[r * 100] = fmaf(acc2[rt][ct][r], 0.0009765625f, acc1[rt][ct][r]);
            }
        }
    }
#undef ISSUE_A
#undef LOADW
#undef BODY
}

// ---------------- fused scan1 + gemm2 + scan2 — scan2 on its own wave ----------------
// 64 blocks x 576 threads:
//   tid 0..99   : scan1 lanes (waves 0-1), 4-deep z prefetch — r11 code verbatim
//   tid 128..511: gemm2 (chunk i-1) + V2 copy-out (chunk i-3) — r11 code, tg=tid-128
//   tid 512..521: scan2 lanes (wave 8; was tid 100-109 = shared wave with scan1,
//                 which serialized BOTH FHN chains on wave 1 every iteration)
// LDS map identical to r11: V1s[2][128][116] @0 (cols 100-109 = V2),
//   z2s[2][128][12] @29696 ; 32768 floats = 128 KB
__global__ __launch_bounds__(576) void fused_scan3(const float* __restrict__ z1p,
                                                   const float* __restrict__ W2,
                                                   float* __restrict__ out) {
    __shared__ float fsm[32768];
    const int tid = threadIdx.x;
    const int b   = blockIdx.x;
    const float dt = FHN_DT;

    float V = 0.f, S = 0.f;
    const float* zb = z1p + (long)b * 2048 * 100 + tid;   // scan1 lanes only
    float z0[16], z1r[16], z2r[16], z3r[16];
    if (tid < 100) {
#pragma unroll
        for (int u = 0; u < 16; ++u) {
            z0[u]  = zb[u * 100];
            z1r[u] = zb[(16 + u) * 100];
            z2r[u] = zb[(32 + u) * 100];
            z3r[u] = zb[(48 + u) * 100];
        }
    }

    const int tg = tid - 128;                             // gemm2 threads: 0..383
    int pp = (tg >> 7) & 3;
    pp = __builtin_amdgcn_readfirstlane(pp);
    const int r  = tg & 127;
    const int mb = (pp == 0) ? 0 : (pp == 1 ? 4 : 7);
    const int mc = (pp == 0) ? 4 : 3;
    const int m2 = tid - 512;                             // scan2 lane id 0..9

    for (int i = 0; i <= 18; ++i) {
        if (tid < 128) {
            // ---- scan1 (r11 verbatim) ----
            bool a1 = (tid < 100) && (i < 16);
            if (a1) {
#pragma unroll
                for (int sub = 0; sub < 8; ++sub) {
                    float zt[16];
                    int tn = (i * 8 + sub + 4) * 16;
                    if (tn < 2048) {
#pragma unroll
                        for (int u = 0; u < 16; ++u) zt[u] = zb[(tn + u) * 100];
                    }
                    const int cw = i & 1;
#pragma unroll
                    for (int u = 0; u < 16; ++u) {
                        int tl = sub * 16 + u;
                        fsm[cw * 14848 + tl * 116 + tid] = V;
                        float z  = z0[u];
                        float V3 = V * V * V;
                        float Vn = fmaf(1.f + dt, V,
                                    fmaf(-dt / 3.f, V3, fmaf(-dt, S, dt * z)));
                        float Sn = fmaf(dt * 0.08f, V + 0.7f - 0.8f * S, S);
                        V = Vn; S = Sn;
                    }
#pragma unroll
                    for (int u = 0; u < 16; ++u) {
                        z0[u] = z1r[u]; z1r[u] = z2r[u]; z2r[u] = z3r[u]; z3r[u] = zt[u];
                    }
                }
            }
        } else if (tid < 512) {
            // ---- gemm2 chunk i-1 + copy-out chunk i-3 (r11 verbatim) ----
            if (i >= 1 && i <= 16) {
                const int pb = (i - 1) & 1;
                float acc[4] = {0.f, 0.f, 0.f, 0.f};
                for (int kq = 0; kq < 25; ++kq) {
                    float4 v = *(const float4*)&fsm[pb * 14848 + r * 116 + kq * 4];
#pragma unroll
                    for (int j = 0; j < 4; ++j) {
                        if (j < mc) {
                            const float* wp = W2 + (mb + j) * 100 + kq * 4;  // uniform -> s_load
                            acc[j] = fmaf(v.x, wp[0], acc[j]);
                            acc[j] = fmaf(v.y, wp[1], acc[j]);
                            acc[j] = fmaf(v.z, wp[2], acc[j]);
                            acc[j] = fmaf(v.w, wp[3], acc[j]);
                        }
                    }
                }
#pragma unroll
                for (int j = 0; j < 4; ++j)
                    if (j < mc) fsm[29696 + pb * 1536 + r * 12 + mb + j] = 0.5f * acc[j];
            }
            if (i >= 3) {
                const int pb = (i - 1) & 1;
                float* dst = out + ((long)b * 2048 + (long)(i - 3) * 128 + r) * 10;
#pragma unroll
                for (int j = 0; j < 4; ++j)
                    if (j < mc) dst[mb + j] = fsm[pb * 14848 + r * 116 + 100 + mb + j];
            }
        } else {
            // ---- scan2 chunk i-2 (r11 code; own wave now) ----
            bool a2 = (m2 < 10) && (i >= 2) && (i < 18);
            if (a2) {
                const int cw = i & 1;
#pragma unroll
                for (int sub = 0; sub < 8; ++sub) {
                    float z0s[16];
#pragma unroll
                    for (int u = 0; u < 16; ++u)
                        z0s[u] = fsm[29696 + cw * 1536 + (sub * 16 + u) * 12 + m2];
#pragma unroll
                    for (int u = 0; u < 16; ++u) {
                        int tl = sub * 16 + u;
                        fsm[cw * 14848 + tl * 116 + 100 + m2] = V;
                        float z  = z0s[u];
                        float V3 = V * V * V;
                        float Vn = fmaf(1.f + dt, V,
                                    fmaf(-dt / 3.f, V3, fmaf(-dt, S, dt * z)));
                        float Sn = fmaf(dt * 0.08f, V + 0.7f - 0.8f * S, S);
                        V = Vn; S = Sn;
                    }
                }
            }
        }
        sync_lds();
    }
}

extern "C" void kernel_launch(void* const* d_in, const int* in_sizes, int n_in,
                              void* d_out, int out_size, void* d_ws, size_t ws_size,
                              hipStream_t stream) {
    const float* batch = (const float*)d_in[0];   // 64*2048*784
    const float* W1    = (const float*)d_in[1];   // 100*784
    const float* W2    = (const float*)d_in[2];   // 10*100
    float* out = (float*)d_out;                   // 64*2048*10

    char* base = (char*)d_ws;
    unsigned short* Wg = (unsigned short*)base;   // 448000 B
    float* z1p = (float*)(base + 448000);         // 131072*100 f32

    prep_w3<<<875, 256, 0, stream>>>(W1, Wg);
    gemm1_n<<<1024, 256, 0, stream>>>(batch, Wg, z1p);
    fused_scan3<<<64, 576, 0, stream>>>(z1p, W2, out);
}

// Round 16
// 188.724 us; speedup vs baseline: 2.4592x; 1.0825x over previous
//
#include <hip/hip_runtime.h>
#include <hip/hip_bf16.h>

// B=64, T=2048, D=784, N1=100, N2=10, dt=0.04
// Pipeline:
//   prep_w16 : W1 -> fp16 2-way split (h, r*1024) in FRAGMENT ORDER for
//              mfma_f32_16x16x32_f16 (r10-proven image): [kt 25][term 2][ct 7][lane 64][e 8]
//   gemm1_w  : z1 = batch @ W1^T, 3-term fp16 split, BARRIER-FREE K-loop.
//              W image persistent in LDS in 3 sections (9+8+8 tiles = 126 KB),
//              bulk-loaded via global_load_lds (vmcnt(0)+barrier only at the 3
//              section boundaries). Per wave: stream A global->reg (2-tile
//              flight), split, conflict-free ds_read_b128 (base+lane*16), MFMA.
//              512 thr (8 waves), BM=256, grid 512. Waves drift freely.
//   fused_scan3: scan1 + gemm2 + scan2 (round-15 version verbatim).
//
// ws: Wg 358400 B | z1p 131072*100 f32 (52.4 MB)

#define FHN_DT 0.04f

typedef _Float16 f16x8 __attribute__((ext_vector_type(8)));
typedef __attribute__((ext_vector_type(4))) float f32x4;

__device__ __forceinline__ void gl16(const void* g, void* l) {
    __builtin_amdgcn_global_load_lds(
        (const __attribute__((address_space(1))) unsigned int*)g,
        (__attribute__((address_space(3))) unsigned int*)l, 16, 0, 0);
}

__device__ __forceinline__ void sync_lds() {
    asm volatile("s_waitcnt lgkmcnt(0)" ::: "memory");
    __builtin_amdgcn_s_barrier();
    asm volatile("" ::: "memory");
}

// ---------------- prep: W1 (100x784) -> fragment-order fp16 split image (r10 verbatim) ----------------
// frag f = term*7 + ct ; short index = kt*7168 + f*512 + l*8 + e
// value: n = ct*16 + (l&15), k = kt*32 + (l>>4)*8 + e   (pad -> 0)
__global__ void prep_w16(const float* __restrict__ W1, unsigned short* __restrict__ Wg) {
    int idx = blockIdx.x * 256 + threadIdx.x;
    if (idx >= 179200) return;
    int kt   = idx / 7168;
    int rem  = idx % 7168;
    int f    = rem >> 9;
    int r2   = rem & 511;
    int l    = r2 >> 3;
    int e    = r2 & 7;
    int term = f / 7, ct = f % 7;
    int n = ct * 16 + (l & 15);
    int k = kt * 32 + (l >> 4) * 8 + e;
    float v = (n < 100 && k < 784) ? W1[n * 784 + k] : 0.0f;
    _Float16 h = (_Float16)v;
    unsigned short o;
    if (term == 0) o = __builtin_bit_cast(unsigned short, h);
    else           o = __builtin_bit_cast(unsigned short, (_Float16)((v - (float)h) * 1024.0f));
    Wg[idx] = o;
}

// ---------------- GEMM1: barrier-free K-loop, W persistent in LDS ----------------
__global__ __launch_bounds__(512, 1) void gemm1_w(const float* __restrict__ A,
                                                  const unsigned short* __restrict__ Wg,
                                                  float* __restrict__ z1p) {
    __shared__ __align__(16) char smem[129024];    // 9 tiles x 14336 B (max section)
    const int tid  = threadIdx.x;                  // 0..511
    const int w    = tid >> 6;                     // 0..7
    const int lane = tid & 63;
    const int ln   = lane & 15;
    const int kg   = lane >> 4;                    // k-slice = kg*8
    const long row0 = (long)blockIdx.x * 256;

    const float* arow0 = A + (row0 + w * 32 + ln) * 784 + kg * 8;
    const float* arow1 = arow0 + (size_t)16 * 784;

    f32x4 acc1[2][7] = {};
    f32x4 acc2[2][7] = {};
    float afpA[16], afpB[16];      // [0..7] row0, [8..15] row1

#define ISSUE_A(T, AF) {                                                        \
        if ((T) == 24 && kg >= 2) {                                             \
            *(float4*)&AF[0]  = make_float4(0.f, 0.f, 0.f, 0.f);                \
            *(float4*)&AF[4]  = make_float4(0.f, 0.f, 0.f, 0.f);                \
            *(float4*)&AF[8]  = make_float4(0.f, 0.f, 0.f, 0.f);                \
            *(float4*)&AF[12] = make_float4(0.f, 0.f, 0.f, 0.f);                \
        } else {                                                                \
            *(float4*)&AF[0]  = *(const float4*)(arow0 + (T) * 32);             \
            *(float4*)&AF[4]  = *(const float4*)(arow0 + (T) * 32 + 4);         \
            *(float4*)&AF[8]  = *(const float4*)(arow1 + (T) * 32);             \
            *(float4*)&AF[12] = *(const float4*)(arow1 + (T) * 32 + 4);         \
        } }

    // bulk W-section copy: linear, wave-uniform base + lane*16 (DMA-native)
#define LOADSEC(TS, NB) {                                                       \
        const char* src_ = (const char*)Wg + (size_t)(TS) * 14336;              \
        _Pragma("unroll 1")                                                     \
        for (int c_ = 0; c_ < (NB) / 8192; ++c_)                                \
            gl16(src_ + c_ * 8192 + tid * 16, smem + c_ * 8192 + tid * 16);     \
        if (((NB) & 8191) != 0 && tid * 16 < ((NB) & 8191))                     \
            gl16(src_ + ((NB) / 8192) * 8192 + tid * 16,                        \
                 smem + ((NB) / 8192) * 8192 + tid * 16);                       \
    }

#define SEC_SYNC() {                                                            \
        asm volatile("s_waitcnt vmcnt(0)" ::: "memory");                        \
        __builtin_amdgcn_s_barrier();                                           \
        asm volatile("" ::: "memory");                                          \
    }

    // barrier-free body: wait own A (compiler vmcnt), split, prefetch, MFMA
#define BODY(KT, AF, TS) {                                                      \
        f16x8 ah0, al0, ah1, al1;                                               \
        _Pragma("unroll")                                                       \
        for (int e_ = 0; e_ < 8; ++e_) {                                        \
            float a0_ = AF[e_], a1_ = AF[8 + e_];                               \
            _Float16 h0_ = (_Float16)a0_, h1_ = (_Float16)a1_;                  \
            ah0[e_] = h0_; ah1[e_] = h1_;                                       \
            al0[e_] = (_Float16)((a0_ - (float)h0_) * 1024.0f);                 \
            al1[e_] = (_Float16)((a1_ - (float)h1_) * 1024.0f);                 \
        }                                                                       \
        if ((KT) < 23) ISSUE_A((KT) + 2, AF);                                   \
        const char* cb_ = smem + ((KT) - (TS)) * 14336 + lane * 16;             \
        _Pragma("unroll")                                                       \
        for (int ct_ = 0; ct_ < 7; ++ct_) {                                     \
            f16x8 bh = *(const f16x8*)(cb_ + ct_ * 1024);                       \
            f16x8 bl = *(const f16x8*)(cb_ + 7168 + ct_ * 1024);                \
            acc1[0][ct_] = __builtin_amdgcn_mfma_f32_16x16x32_f16(ah0, bh, acc1[0][ct_], 0, 0, 0); \
            acc2[0][ct_] = __builtin_amdgcn_mfma_f32_16x16x32_f16(ah0, bl, acc2[0][ct_], 0, 0, 0); \
            acc2[0][ct_] = __builtin_amdgcn_mfma_f32_16x16x32_f16(al0, bh, acc2[0][ct_], 0, 0, 0); \
            acc1[1][ct_] = __builtin_amdgcn_mfma_f32_16x16x32_f16(ah1, bh, acc1[1][ct_], 0, 0, 0); \
            acc2[1][ct_] = __builtin_amdgcn_mfma_f32_16x16x32_f16(ah1, bl, acc2[1][ct_], 0, 0, 0); \
            acc2[1][ct_] = __builtin_amdgcn_mfma_f32_16x16x32_f16(al1, bh, acc2[1][ct_], 0, 0, 0); \
        } }

    // prologue: A tiles 0,1 in flight (drained by first SEC_SYNC; values kept)
    ISSUE_A(0, afpA);
    ISSUE_A(1, afpB);

    // ---- section 0: tiles 0..8 (9 x 14336 = 129024 B) ----
    LOADSEC(0, 129024);
    SEC_SYNC();
#pragma unroll 1
    for (int k0 = 0; k0 < 8; k0 += 2) { BODY(k0, afpA, 0); BODY(k0 + 1, afpB, 0); }
    BODY(8, afpA, 0);

    // ---- section 1: tiles 9..16 (8 x 14336 = 114688 B) ----
    asm volatile("" ::: "memory");
    __builtin_amdgcn_s_barrier();      // all waves done reading section 0
    asm volatile("" ::: "memory");
    LOADSEC(9, 114688);
    SEC_SYNC();
#pragma unroll 1
    for (int k0 = 9; k0 < 17; k0 += 2) { BODY(k0, afpB, 9); BODY(k0 + 1, afpA, 9); }

    // ---- section 2: tiles 17..24 ----
    asm volatile("" ::: "memory");
    __builtin_amdgcn_s_barrier();
    asm volatile("" ::: "memory");
    LOADSEC(17, 114688);
    SEC_SYNC();
#pragma unroll 1
    for (int k0 = 17; k0 < 25; k0 += 2) { BODY(k0, afpB, 17); BODY(k0 + 1, afpA, 17); }

    // ---- epilogue: C/D map col = lane&15, row = kg*4 + r ; z = acc1 + acc2/1024 ----
#pragma unroll
    for (int ct = 0; ct < 7; ++ct) {
        int n = ct * 16 + ln;
        if (n < 100) {
#pragma unroll
            for (int rt = 0; rt < 2; ++rt) {
                long rg = row0 + w * 32 + rt * 16 + kg * 4;
                float* p = z1p + rg * 100 + n;
#pragma unroll
                for (int r = 0; r < 4; ++r)
                    p[r * 100] = fmaf(acc2[rt][ct][r], 0.0009765625f, acc1[rt][ct][r]);
            }
        }
    }
#undef ISSUE_A
#undef LOADSEC
#undef SEC_SYNC
#undef BODY
}

// ---------------- fused scan1 + gemm2 + scan2 — r15 version verbatim ----------------
__global__ __launch_bounds__(576) void fused_scan3(const float* __restrict__ z1p,
                                                   const float* __restrict__ W2,
                                                   float* __restrict__ out) {
    __shared__ float fsm[32768];
    const int tid = threadIdx.x;
    const int b   = blockIdx.x;
    const float dt = FHN_DT;

    float V = 0.f, S = 0.f;
    const float* zb = z1p + (long)b * 2048 * 100 + tid;   // scan1 lanes only
    float z0[16], z1r[16], z2r[16], z3r[16];
    if (tid < 100) {
#pragma unroll
        for (int u = 0; u < 16; ++u) {
            z0[u]  = zb[u * 100];
            z1r[u] = zb[(16 + u) * 100];
            z2r[u] = zb[(32 + u) * 100];
            z3r[u] = zb[(48 + u) * 100];
        }
    }

    const int tg = tid - 128;                             // gemm2 threads: 0..383
    int pp = (tg >> 7) & 3;
    pp = __builtin_amdgcn_readfirstlane(pp);
    const int r  = tg & 127;
    const int mb = (pp == 0) ? 0 : (pp == 1 ? 4 : 7);
    const int mc = (pp == 0) ? 4 : 3;
    const int m2 = tid - 512;                             // scan2 lane id 0..9

    for (int i = 0; i <= 18; ++i) {
        if (tid < 128) {
            bool a1 = (tid < 100) && (i < 16);
            if (a1) {
#pragma unroll
                for (int sub = 0; sub < 8; ++sub) {
                    float zt[16];
                    int tn = (i * 8 + sub + 4) * 16;
                    if (tn < 2048) {
#pragma unroll
                        for (int u = 0; u < 16; ++u) zt[u] = zb[(tn + u) * 100];
                    }
                    const int cw = i & 1;
#pragma unroll
                    for (int u = 0; u < 16; ++u) {
                        int tl = sub * 16 + u;
                        fsm[cw * 14848 + tl * 116 + tid] = V;
                        float z  = z0[u];
                        float V3 = V * V * V;
                        float Vn = fmaf(1.f + dt, V,
                                    fmaf(-dt / 3.f, V3, fmaf(-dt, S, dt * z)));
                        float Sn = fmaf(dt * 0.08f, V + 0.7f - 0.8f * S, S);
                        V = Vn; S = Sn;
                    }
#pragma unroll
                    for (int u = 0; u < 16; ++u) {
                        z0[u] = z1r[u]; z1r[u] = z2r[u]; z2r[u] = z3r[u]; z3r[u] = zt[u];
                    }
                }
            }
        } else if (tid < 512) {
            if (i >= 1 && i <= 16) {
                const int pb = (i - 1) & 1;
                float acc[4] = {0.f, 0.f, 0.f, 0.f};
                for (int kq = 0; kq < 25; ++kq) {
                    float4 v = *(const float4*)&fsm[pb * 14848 + r * 116 + kq * 4];
#pragma unroll
                    for (int j = 0; j < 4; ++j) {
                        if (j < mc) {
                            const float* wp = W2 + (mb + j) * 100 + kq * 4;  // uniform -> s_load
                            acc[j] = fmaf(v.x, wp[0], acc[j]);
                            acc[j] = fmaf(v.y, wp[1], acc[j]);
                            acc[j] = fmaf(v.z, wp[2], acc[j]);
                            acc[j] = fmaf(v.w, wp[3], acc[j]);
                        }
                    }
                }
#pragma unroll
                for (int j = 0; j < 4; ++j)
                    if (j < mc) fsm[29696 + pb * 1536 + r * 12 + mb + j] = 0.5f * acc[j];
            }
            if (i >= 3) {
                const int pb = (i - 1) & 1;
                float* dst = out + ((long)b * 2048 + (long)(i - 3) * 128 + r) * 10;
#pragma unroll
                for (int j = 0; j < 4; ++j)
                    if (j < mc) dst[mb + j] = fsm[pb * 14848 + r * 116 + 100 + mb + j];
            }
        } else {
            bool a2 = (m2 < 10) && (i >= 2) && (i < 18);
            if (a2) {
                const int cw = i & 1;
#pragma unroll
                for (int sub = 0; sub < 8; ++sub) {
                    float z0s[16];
#pragma unroll
                    for (int u = 0; u < 16; ++u)
                        z0s[u] = fsm[29696 + cw * 1536 + (sub * 16 + u) * 12 + m2];
#pragma unroll
                    for (int u = 0; u < 16; ++u) {
                        int tl = sub * 16 + u;
                        fsm[cw * 14848 + tl * 116 + 100 + m2] = V;
                        float z  = z0s[u];
                        float V3 = V * V * V;
                        float Vn = fmaf(1.f + dt, V,
                                    fmaf(-dt / 3.f, V3, fmaf(-dt, S, dt * z)));
                        float Sn = fmaf(dt * 0.08f, V + 0.7f - 0.8f * S, S);
                        V = Vn; S = Sn;
                    }
                }
            }
        }
        sync_lds();
    }
}

extern "C" void kernel_launch(void* const* d_in, const int* in_sizes, int n_in,
                              void* d_out, int out_size, void* d_ws, size_t ws_size,
                              hipStream_t stream) {
    const float* batch = (const float*)d_in[0];   // 64*2048*784
    const float* W1    = (const float*)d_in[1];   // 100*784
    const float* W2    = (const float*)d_in[2];   // 10*100
    float* out = (float*)d_out;                   // 64*2048*10

    char* base = (char*)d_ws;
    unsigned short* Wg = (unsigned short*)base;   // 358400 B
    float* z1p = (float*)(base + 358400);         // 131072*100 f32

    prep_w16<<<700, 256, 0, stream>>>(W1, Wg);
    gemm1_w<<<512, 512, 0, stream>>>(batch, Wg, z1p);
    fused_scan3<<<64, 576, 0, stream>>>(z1p, W2, out);
}